// Round 4
// baseline (525.255 us; speedup 1.0000x reference)
//
#include <hip/hip_runtime.h>

// NFTM1DLearnable: 1-D heat equation, B=128 rows, N=16384, T=64 states out.
// out[b][t][0][n], fp32. alpha = clip(exp(log_alpha), 1e-3, 1.0).
//
// Strategy: trapezoidal temporal blocking. Each block owns a CHUNK of one
// row, loads CHUNK + 2*(T-1) halo into LDS, runs all 63 steps locally
// (validity shrinks by 1/side/step except at true row boundaries where the
// clamped stencil is exact), and writes its CHUNK slice of every state.

constexpr int   T_STEPS  = 64;
constexpr int   N_COLS   = 16384;
constexpr int   CHUNK    = 2048;
constexpr int   HALO     = T_STEPS - 1;           // 63
constexpr int   EXT      = CHUNK + 2 * HALO;      // 2174
constexpr int   NTHREADS = 256;
constexpr float ALPHA_MIN = 0.001f;
constexpr float ALPHA_MAX = 1.0f;

__global__ __launch_bounds__(NTHREADS)
void heat1d_kernel(const float* __restrict__ f0,
                   const float* __restrict__ log_alpha,
                   float* __restrict__ out)
{
    __shared__ float buf0[EXT];
    __shared__ float buf1[EXT];

    constexpr int CHUNKS_PER_ROW = N_COLS / CHUNK;            // 8
    const int b  = blockIdx.x / CHUNKS_PER_ROW;
    const int ci = blockIdx.x % CHUNKS_PER_ROW;
    const int c0 = ci * CHUNK;

    const int ext_lo = (c0 - HALO < 0) ? 0 : (c0 - HALO);
    const int ext_hi = (c0 + CHUNK + HALO > N_COLS) ? N_COLS : (c0 + CHUNK + HALO);
    const int ext_n  = ext_hi - ext_lo;

    const float alpha = fminf(fmaxf(expf(log_alpha[0]), ALPHA_MIN), ALPHA_MAX);

    const float* __restrict__ row  = f0  + (size_t)b * N_COLS;
    float*       __restrict__ orow = out + (size_t)b * T_STEPS * N_COLS;

    // Load extended region; write state t=0 for our chunk.
    for (int e = threadIdx.x; e < ext_n; e += NTHREADS) {
        const int n = ext_lo + e;
        const float v = row[n];
        buf0[e] = v;
        if (n >= c0 && n < c0 + CHUNK) orow[n] = v;
    }
    __syncthreads();

    float* cur = buf0;
    float* nxt = buf1;

    for (int t = 1; t < T_STEPS; ++t) {
        // Region of x_t we can (and need to) compute.
        const int lo_t = (ext_lo == 0)      ? 0      : (ext_lo + t);
        const int hi_t = (ext_hi == N_COLS) ? N_COLS : (ext_hi - t);
        float* __restrict__ od = orow + (size_t)t * N_COLS;

        for (int n = lo_t + (int)threadIdx.x; n < hi_t; n += NTHREADS) {
            const int e = n - ext_lo;
            const float xc = cur[e];
            const float xm = (n == 0)          ? xc : cur[e - 1];
            const float xp = (n == N_COLS - 1) ? xc : cur[e + 1];
            const float v  = xc + alpha * (xm - 2.0f * xc + xp);
            nxt[e] = v;
            if (n >= c0 && n < c0 + CHUNK) od[n] = v;
        }
        __syncthreads();
        float* tmp = cur; cur = nxt; nxt = tmp;
    }
}

extern "C" void kernel_launch(void* const* d_in, const int* in_sizes, int n_in,
                              void* d_out, int out_size, void* d_ws, size_t ws_size,
                              hipStream_t stream)
{
    const float* f0        = (const float*)d_in[0];
    const float* log_alpha = (const float*)d_in[1];
    float*       out       = (float*)d_out;

    constexpr int B = 128;
    constexpr int CHUNKS_PER_ROW = N_COLS / CHUNK;   // 8
    const dim3 grid(B * CHUNKS_PER_ROW);             // 1024 blocks
    const dim3 block(NTHREADS);

    heat1d_kernel<<<grid, block, 0, stream>>>(f0, log_alpha, out);
}